// Round 11
// baseline (2318.468 us; speedup 1.0000x reference)
//
#include <hip/hip_runtime.h>
#include <hip/hip_bf16.h>
#include <hip/hip_cooperative_groups.h>
#include <math.h>

namespace cg = cooperative_groups;

// ---------------------------------------------------------------------------
// ModelPassMessage: 7-layer graph conv.
// R1..R6: CSR->slot-table, bf16 everywhere, LDS-free conv. 1631->419us.
// R7 FAILED (fused gather+conv restructured gather serially). 510us.
// R8: 4B packed slots (prep writes = atomic RMW lines, ~neutral). 413us.
// R9 FAILED (413->2123): cooperative fused_all with launch_bounds(512,4)
//     capped VGPR at 64 -> massive scratch spill (FETCH 420MB). Structure
//     was sound (correct, capturable); occupancy bound broke it.
// R10: cooperative retry, spill-free: 256-thread blocks, launch_bounds(256,4)
//     (VGPR cap 128 > conv's ~90). Conv = 4 waves x dual j-slice (acc[2][8],
//     both W rows wave-uniform scalar). Final layer fused wave-locally
//     (aggr never round-trips). 13 grid.sync()s replace 16 dispatch gaps.
// ---------------------------------------------------------------------------

typedef __hip_bfloat16 bf16;

#define SLOTW 64  // max degree supported; Poisson(16) max over 50k nodes ~45

__device__ inline float b2f(unsigned u) {
    return __uint_as_float(u << 16);
}
__device__ inline unsigned short f2b(float f) {
    union { float f; unsigned u; } v;
    v.f = f;
    unsigned r = v.u + 0x7FFF + ((v.u >> 16) & 1);  // RNE
    return (unsigned short)(r >> 16);
}
__device__ inline float4 ld4(const bf16* row, int kc) {
    ushort4 u = ((const ushort4*)row)[kc];
    float4 r;
    r.x = b2f(u.x); r.y = b2f(u.y); r.z = b2f(u.z); r.w = b2f(u.w);
    return r;
}

// one-node gather: whole wave; 8 edge-groups x 8 lanes x 16B, 16 rows in
// flight (unroll 2). After the reduce, lanes 0..7 hold the aggr row
// (lane p = features [8p,8p+8)). STORE: write packed row to aggr.
template <bool HE, bool STORE>
__device__ __forceinline__ void gather_node(
    const unsigned short* __restrict__ hs, const int* __restrict__ deg,
    const unsigned* __restrict__ slots, bf16* __restrict__ aggr,
    float* __restrict__ he, int node, int lane, float* a /*[8] out*/) {
    int e = deg[node];
    e = e < SLOTW ? e : SLOTW;
    const unsigned* row = slots + (size_t)node * SLOTW;
    const int eg = lane >> 3;
    const int fo = (lane & 7) * 8;

    float a0 = 0.f, a1 = 0.f, a2 = 0.f, a3 = 0.f;
    float a4 = 0.f, a5 = 0.f, a6 = 0.f, a7 = 0.f, efacc = 0.f;
    int i = eg;
    for (; i + 8 < e; i += 16) {
        unsigned p0 = row[i];
        unsigned p1 = row[i + 8];
        uint4 u0 = *(const uint4*)(hs + (size_t)(p0 & 0xffff) * 64 + fo);
        uint4 u1 = *(const uint4*)(hs + (size_t)(p1 & 0xffff) * 64 + fo);
        if (HE) efacc += b2f(p0 >> 16) + b2f(p1 >> 16);
        a0 += b2f(u0.x & 0xffff) + b2f(u1.x & 0xffff);
        a1 += b2f(u0.x >> 16) + b2f(u1.x >> 16);
        a2 += b2f(u0.y & 0xffff) + b2f(u1.y & 0xffff);
        a3 += b2f(u0.y >> 16) + b2f(u1.y >> 16);
        a4 += b2f(u0.z & 0xffff) + b2f(u1.z & 0xffff);
        a5 += b2f(u0.z >> 16) + b2f(u1.z >> 16);
        a6 += b2f(u0.w & 0xffff) + b2f(u1.w & 0xffff);
        a7 += b2f(u0.w >> 16) + b2f(u1.w >> 16);
    }
    if (i < e) {
        unsigned p0 = row[i];
        uint4 u0 = *(const uint4*)(hs + (size_t)(p0 & 0xffff) * 64 + fo);
        if (HE) efacc += b2f(p0 >> 16);
        a0 += b2f(u0.x & 0xffff);
        a1 += b2f(u0.x >> 16);
        a2 += b2f(u0.y & 0xffff);
        a3 += b2f(u0.y >> 16);
        a4 += b2f(u0.z & 0xffff);
        a5 += b2f(u0.z >> 16);
        a6 += b2f(u0.w & 0xffff);
        a7 += b2f(u0.w >> 16);
    }
#pragma unroll
    for (int off = 32; off >= 8; off >>= 1) {
        a0 += __shfl_down(a0, off, 64);
        a1 += __shfl_down(a1, off, 64);
        a2 += __shfl_down(a2, off, 64);
        a3 += __shfl_down(a3, off, 64);
        a4 += __shfl_down(a4, off, 64);
        a5 += __shfl_down(a5, off, 64);
        a6 += __shfl_down(a6, off, 64);
        a7 += __shfl_down(a7, off, 64);
        if (HE) efacc += __shfl_down(efacc, off, 64);
    }
    if (HE && lane == 0) he[node] = efacc;
    if (STORE && lane < 8) {
        uint4 pk;
        pk.x = (unsigned)f2b(a0) | ((unsigned)f2b(a1) << 16);
        pk.y = (unsigned)f2b(a2) | ((unsigned)f2b(a3) << 16);
        pk.z = (unsigned)f2b(a4) | ((unsigned)f2b(a5) << 16);
        pk.w = (unsigned)f2b(a6) | ((unsigned)f2b(a7) << 16);
        *(uint4*)((unsigned short*)aggr + (size_t)node * 64 + fo) = pk;
    }
    a[0] = a0; a[1] = a1; a[2] = a2; a[3] = a3;
    a[4] = a4; a[5] = a5; a[6] = a6; a[7] = a7;
}

// one 64-node conv tile with 4 waves: lane = node; wave wv accumulates TWO
// j-slices (8*wv and 8*wv+32) in a single k-pass. Both W row addresses are
// wave-uniform -> scalar operands.
#define JPW 8
__device__ __forceinline__ void conv_tile(
    const bf16* __restrict__ h, const bf16* __restrict__ aggr,
    const float* __restrict__ he, const float* __restrict__ Wl,
    const float* __restrict__ bias, bf16* __restrict__ outp, int n_nodes,
    int act, int base, int lane, int wv) {
    const int j0a = wv * JPW;        // 0,8,16,24
    const int j0b = j0a + 32;        // 32,40,48,56
    int node = base + lane;
    bool ok = node < n_nodes;
    int nc = ok ? node : (n_nodes - 1);

    const bf16* hrow = h + (size_t)nc * 64;
    const bf16* arow = aggr + (size_t)nc * 64;

    float acca[JPW], accb[JPW];
#pragma unroll
    for (int jj = 0; jj < JPW; ++jj) {
        acca[jj] = bias[j0a + jj];
        accb[jj] = bias[j0b + jj];
    }
    {
        float hev = he[nc];
        const float* wra = Wl + 128 * 64 + j0a;
        const float* wrb = Wl + 128 * 64 + j0b;
#pragma unroll
        for (int jj = 0; jj < JPW; ++jj) {
            acca[jj] += hev * wra[jj];
            accb[jj] += hev * wrb[jj];
        }
    }
#pragma unroll 2
    for (int kc = 0; kc < 16; ++kc) {
        float4 xv = ld4(hrow, kc);
        const float* wra = Wl + (kc * 4) * 64 + j0a;
        const float* wrb = Wl + (kc * 4) * 64 + j0b;
#pragma unroll
        for (int jj = 0; jj < JPW; ++jj) {
            acca[jj] += xv.x * wra[jj];
            accb[jj] += xv.x * wrb[jj];
        }
#pragma unroll
        for (int jj = 0; jj < JPW; ++jj) {
            acca[jj] += xv.y * wra[64 + jj];
            accb[jj] += xv.y * wrb[64 + jj];
        }
#pragma unroll
        for (int jj = 0; jj < JPW; ++jj) {
            acca[jj] += xv.z * wra[128 + jj];
            accb[jj] += xv.z * wrb[128 + jj];
        }
#pragma unroll
        for (int jj = 0; jj < JPW; ++jj) {
            acca[jj] += xv.w * wra[192 + jj];
            accb[jj] += xv.w * wrb[192 + jj];
        }
    }
#pragma unroll 2
    for (int kc = 0; kc < 16; ++kc) {
        float4 xv = ld4(arow, kc);
        const float* wra = Wl + (64 + kc * 4) * 64 + j0a;
        const float* wrb = Wl + (64 + kc * 4) * 64 + j0b;
#pragma unroll
        for (int jj = 0; jj < JPW; ++jj) {
            acca[jj] += xv.x * wra[jj];
            accb[jj] += xv.x * wrb[jj];
        }
#pragma unroll
        for (int jj = 0; jj < JPW; ++jj) {
            acca[jj] += xv.y * wra[64 + jj];
            accb[jj] += xv.y * wrb[64 + jj];
        }
#pragma unroll
        for (int jj = 0; jj < JPW; ++jj) {
            acca[jj] += xv.z * wra[128 + jj];
            accb[jj] += xv.z * wrb[128 + jj];
        }
#pragma unroll
        for (int jj = 0; jj < JPW; ++jj) {
            acca[jj] += xv.w * wra[192 + jj];
            accb[jj] += xv.w * wrb[192 + jj];
        }
    }
    if (ok) {
        unsigned short usa[JPW], usb[JPW];
#pragma unroll
        for (int jj = 0; jj < JPW; ++jj) {
            float va = acca[jj], vb = accb[jj];
            if (act == 1) {
                va = fmaxf(va, 0.f);
                vb = fmaxf(vb, 0.f);
            } else {
                va = 1.f / (1.f + expf(-va));
                vb = 1.f / (1.f + expf(-vb));
            }
            usa[jj] = f2b(va);
            usb[jj] = f2b(vb);
        }
        uint4 pa, pb;
        pa.x = (unsigned)usa[0] | ((unsigned)usa[1] << 16);
        pa.y = (unsigned)usa[2] | ((unsigned)usa[3] << 16);
        pa.z = (unsigned)usa[4] | ((unsigned)usa[5] << 16);
        pa.w = (unsigned)usa[6] | ((unsigned)usa[7] << 16);
        pb.x = (unsigned)usb[0] | ((unsigned)usb[1] << 16);
        pb.y = (unsigned)usb[2] | ((unsigned)usb[3] << 16);
        pb.z = (unsigned)usb[4] | ((unsigned)usb[5] << 16);
        pb.w = (unsigned)usb[6] | ((unsigned)usb[7] << 16);
        unsigned short* op = (unsigned short*)outp + (size_t)node * 64;
        *(uint4*)(op + j0a) = pa;
        *(uint4*)(op + j0b) = pb;
    }
}

// ---------------- the whole model in one cooperative kernel ----------------
extern "C" __global__ void __launch_bounds__(256, 4) fused_all(
    const float* __restrict__ node_feat, const float* __restrict__ edge_feat,
    const int* __restrict__ src, const int* __restrict__ dst,
    const float* __restrict__ W1, const float* __restrict__ b1,
    const float* __restrict__ Wmid, const float* __restrict__ bmid,
    const float* __restrict__ W2, const float* __restrict__ b2,
    float* __restrict__ out, float* __restrict__ he, float* __restrict__ Wt,
    bf16* __restrict__ aggr, bf16* __restrict__ hA, bf16* __restrict__ hB,
    bf16* __restrict__ nfb, unsigned* __restrict__ slots,
    int* __restrict__ deg, int N, int E) {
    cg::grid_group grid = cg::this_grid();
    const int tid = blockIdx.x * blockDim.x + threadIdx.x;
    const int T = gridDim.x * blockDim.x;
    const int lane = threadIdx.x & 63;
    const int wv = __builtin_amdgcn_readfirstlane(threadIdx.x >> 6);  // 0..3
    const int wid = blockIdx.x * 4 + wv;
    const int NW = gridDim.x * 4;
    float areg[8];

    // P1: slot fill + W transpose + node_feat -> bf16 (deg zeroed by memset)
    for (int e = tid; e < E; e += T) {
        int d = dst[e];
        int p = atomicAdd(&deg[d], 1);
        if (p < SLOTW) {
            slots[(size_t)d * SLOTW + p] =
                (unsigned)(src[e] & 0xffff) | ((unsigned)f2b(edge_feat[e]) << 16);
        }
    }
    const int per_layer = 129 * 64;
    for (int idx = tid; idx < 6 * per_layer; idx += T) {
        int l = idx / per_layer;
        int r = idx - l * per_layer;
        int k = r >> 6;
        int j = r & 63;
        const float* Wsrc = (l == 0) ? W1 : Wmid + (size_t)(l - 1) * 64 * 129;
        Wt[idx] = Wsrc[j * 129 + k];
    }
    const int n_quads = N * 16;
    for (int q = tid; q < n_quads; q += T) {
        float4 v = ((const float4*)node_feat)[q];
        ushort4 u;
        u.x = f2b(v.x); u.y = f2b(v.y); u.z = f2b(v.z); u.w = f2b(v.w);
        ((ushort4*)nfb)[q] = u;
    }
    __threadfence();
    grid.sync();

    // 6 hidden layers: gather -> sync -> conv -> sync
    const bf16* hin = nfb;
    bf16* bufs[2] = {hA, hB};
    for (int l = 0; l < 6; ++l) {
        const unsigned short* hs = (const unsigned short*)hin;
        if (l == 0) {
            for (int node = wid; node < N; node += NW)
                gather_node<true, true>(hs, deg, slots, aggr, he, node, lane,
                                        areg);
        } else {
            for (int node = wid; node < N; node += NW)
                gather_node<false, true>(hs, deg, slots, aggr, he, node, lane,
                                         areg);
        }
        __threadfence();
        grid.sync();

        const float* Wl = Wt + (size_t)l * 129 * 64;
        const float* bias = (l == 0) ? b1 : bmid + (size_t)(l - 1) * 64;
        int act = (l == 5) ? 2 : 1;
        bf16* hout = bufs[l & 1];
        for (int base = blockIdx.x * 64; base < N; base += gridDim.x * 64)
            conv_tile(hin, aggr, he, Wl, bias, hout, N, act, base, lane, wv);
        __threadfence();
        grid.sync();
        hin = hout;
    }

    // final layer fused wave-locally: gather leaves the aggr row in lanes
    // 0..7 (lane p = features [8p,8p+8)); compute the 2-class dot in place.
    {
        const unsigned short* hs = (const unsigned short*)hin;
        const int p = lane & 7;
        // per-lane W slices (node-invariant, hoisted)
        float w0a[8], w0b[8], w1a[8], w1b[8];
#pragma unroll
        for (int i = 0; i < 8; ++i) {
            w0a[i] = W2[8 * p + i];
            w0b[i] = W2[64 + 8 * p + i];
            w1a[i] = W2[129 + 8 * p + i];
            w1b[i] = W2[193 + 8 * p + i];
        }
        for (int node = wid; node < N; node += NW) {
            gather_node<false, false>(hs, deg, slots, aggr, he, node, lane,
                                      areg);
            // h features [8p,8p+8) for this node
            uint4 hu = *(const uint4*)(hs + (size_t)node * 64 + 8 * p);
            float x0[8];
            x0[0] = b2f(hu.x & 0xffff); x0[1] = b2f(hu.x >> 16);
            x0[2] = b2f(hu.y & 0xffff); x0[3] = b2f(hu.y >> 16);
            x0[4] = b2f(hu.z & 0xffff); x0[5] = b2f(hu.z >> 16);
            x0[6] = b2f(hu.w & 0xffff); x0[7] = b2f(hu.w >> 16);
            float s0 = 0.f, s1 = 0.f;
#pragma unroll
            for (int i = 0; i < 8; ++i) {
                s0 += w0a[i] * x0[i] + w0b[i] * areg[i];
                s1 += w1a[i] * x0[i] + w1b[i] * areg[i];
            }
            if (lane >= 8) { s0 = 0.f; s1 = 0.f; }
#pragma unroll
            for (int off = 32; off; off >>= 1) {
                s0 += __shfl_down(s0, off, 64);
                s1 += __shfl_down(s1, off, 64);
            }
            if (lane == 0) {
                float hev = he[node];
                out[(size_t)node * 2] = s0 + W2[128] * hev + b2[0];
                out[(size_t)node * 2 + 1] = s1 + W2[257] * hev + b2[1];
            }
        }
    }
}

extern "C" void kernel_launch(void* const* d_in, const int* in_sizes, int n_in,
                              void* d_out, int out_size, void* d_ws,
                              size_t ws_size, hipStream_t stream) {
    const float* node_feat = (const float*)d_in[0];
    const float* edge_feat = (const float*)d_in[1];
    const int* src = (const int*)d_in[2];
    const int* dst = (const int*)d_in[3];
    const float* W1 = (const float*)d_in[4];
    const float* b1 = (const float*)d_in[5];
    const float* Wmid = (const float*)d_in[6];
    const float* bmid = (const float*)d_in[7];
    const float* W2 = (const float*)d_in[8];
    const float* b2 = (const float*)d_in[9];
    float* out = (float*)d_out;

    int N = in_sizes[0] / 64;  // 50000
    int E = in_sizes[1];       // 800000

    // workspace layout (all sections 16B-aligned)
    float* he = (float*)d_ws;                             // N f32
    float* Wt = he + N;                                   // 6*129*64 f32
    bf16* aggr = (bf16*)(Wt + 6 * 129 * 64);              // N*64 bf16
    bf16* hA = aggr + (size_t)N * 64;                     // N*64 bf16
    bf16* hB = hA + (size_t)N * 64;                       // N*64 bf16
    bf16* nfb = hB + (size_t)N * 64;                      // N*64 bf16
    unsigned* slots = (unsigned*)(nfb + (size_t)N * 64);  // N*SLOTW
    int* deg = (int*)(slots + (size_t)N * SLOTW);         // N

    hipMemsetAsync(deg, 0, (size_t)N * sizeof(int), stream);

    int maxB = 0;
    hipOccupancyMaxActiveBlocksPerMultiprocessor(&maxB, (const void*)fused_all,
                                                 256, 0);
    if (maxB < 1) maxB = 1;
    if (maxB > 4) maxB = 4;
    int grid = 256 * maxB;  // target 1024 blocks (4 blocks/CU, 16 waves/CU)

    void* args[] = {(void*)&node_feat, (void*)&edge_feat, (void*)&src,
                    (void*)&dst,       (void*)&W1,        (void*)&b1,
                    (void*)&Wmid,      (void*)&bmid,      (void*)&W2,
                    (void*)&b2,        (void*)&out,       (void*)&he,
                    (void*)&Wt,        (void*)&aggr,      (void*)&hA,
                    (void*)&hB,        (void*)&nfb,       (void*)&slots,
                    (void*)&deg,       (void*)&N,         (void*)&E};
    hipLaunchCooperativeKernel((const void*)fused_all, dim3(grid), dim3(256),
                               args, 0, stream);
}

// Round 12
// 2067.587 us; speedup vs baseline: 1.1213x; 1.1213x over previous
//
#include <hip/hip_runtime.h>
#include <hip/hip_bf16.h>
#include <hip/hip_cooperative_groups.h>
#include <math.h>

namespace cg = cooperative_groups;

// ---------------------------------------------------------------------------
// ModelPassMessage: 7-layer graph conv.
// R1..R6: CSR->slot-table, bf16 everywhere, LDS-free conv. 1631->419us.
// R7 FAILED: block-local gather+conv fusion (serial per-wave gather). 510us.
// R8: 4B packed slots. 413us (best multi-kernel).
// R9/R10 FAILED (2.1-2.3ms): cooperative fused_all with launch_bounds
//     second arg (4) -> VGPR capped at 64 (standalone conv needs 88) ->
//     scratch spill, FETCH 420-441MB of HBM scratch round-trips.
// R11: same cooperative structure, spill variable isolated: launch_bounds(512)
//     with NO min-waves arg (matches known-good conv64 compile), 8-wave
//     blocks, phase bodies verbatim from R8 kernels, no dynamic local
//     indexing. Grid sized by occupancy query.
// ---------------------------------------------------------------------------

typedef __hip_bfloat16 bf16;

#define SLOTW 64  // max degree supported; Poisson(16) max over 50k nodes ~45
#define JPW 8

__device__ inline float b2f(unsigned u) {
    return __uint_as_float(u << 16);
}
__device__ inline unsigned short f2b(float f) {
    union { float f; unsigned u; } v;
    v.f = f;
    unsigned r = v.u + 0x7FFF + ((v.u >> 16) & 1);  // RNE
    return (unsigned short)(r >> 16);
}
__device__ inline float4 ld4(const bf16* row, int kc) {
    ushort4 u = ((const ushort4*)row)[kc];
    float4 r;
    r.x = b2f(u.x); r.y = b2f(u.y); r.z = b2f(u.z); r.w = b2f(u.w);
    return r;
}

// one-node gather (verbatim R8 body): whole wave; 8 edge-groups x 8 lanes x
// 16B, 16 rows in flight (unroll 2); lanes<8 store packed bf16 aggr row.
template <bool HE>
__device__ __forceinline__ void gather_node(
    const unsigned short* __restrict__ hs, const int* __restrict__ deg,
    const unsigned* __restrict__ slots, bf16* __restrict__ aggr,
    float* __restrict__ he, int node, int lane) {
    int e = deg[node];
    e = e < SLOTW ? e : SLOTW;
    const unsigned* row = slots + (size_t)node * SLOTW;
    const int eg = lane >> 3;
    const int fo = (lane & 7) * 8;

    float a0 = 0.f, a1 = 0.f, a2 = 0.f, a3 = 0.f;
    float a4 = 0.f, a5 = 0.f, a6 = 0.f, a7 = 0.f, efacc = 0.f;
    int i = eg;
    for (; i + 8 < e; i += 16) {
        unsigned p0 = row[i];
        unsigned p1 = row[i + 8];
        uint4 u0 = *(const uint4*)(hs + (size_t)(p0 & 0xffff) * 64 + fo);
        uint4 u1 = *(const uint4*)(hs + (size_t)(p1 & 0xffff) * 64 + fo);
        if (HE) efacc += b2f(p0 >> 16) + b2f(p1 >> 16);
        a0 += b2f(u0.x & 0xffff) + b2f(u1.x & 0xffff);
        a1 += b2f(u0.x >> 16) + b2f(u1.x >> 16);
        a2 += b2f(u0.y & 0xffff) + b2f(u1.y & 0xffff);
        a3 += b2f(u0.y >> 16) + b2f(u1.y >> 16);
        a4 += b2f(u0.z & 0xffff) + b2f(u1.z & 0xffff);
        a5 += b2f(u0.z >> 16) + b2f(u1.z >> 16);
        a6 += b2f(u0.w & 0xffff) + b2f(u1.w & 0xffff);
        a7 += b2f(u0.w >> 16) + b2f(u1.w >> 16);
    }
    if (i < e) {
        unsigned p0 = row[i];
        uint4 u0 = *(const uint4*)(hs + (size_t)(p0 & 0xffff) * 64 + fo);
        if (HE) efacc += b2f(p0 >> 16);
        a0 += b2f(u0.x & 0xffff);
        a1 += b2f(u0.x >> 16);
        a2 += b2f(u0.y & 0xffff);
        a3 += b2f(u0.y >> 16);
        a4 += b2f(u0.z & 0xffff);
        a5 += b2f(u0.z >> 16);
        a6 += b2f(u0.w & 0xffff);
        a7 += b2f(u0.w >> 16);
    }
#pragma unroll
    for (int off = 32; off >= 8; off >>= 1) {
        a0 += __shfl_down(a0, off, 64);
        a1 += __shfl_down(a1, off, 64);
        a2 += __shfl_down(a2, off, 64);
        a3 += __shfl_down(a3, off, 64);
        a4 += __shfl_down(a4, off, 64);
        a5 += __shfl_down(a5, off, 64);
        a6 += __shfl_down(a6, off, 64);
        a7 += __shfl_down(a7, off, 64);
        if (HE) efacc += __shfl_down(efacc, off, 64);
    }
    if (HE && lane == 0) he[node] = efacc;
    if (lane < 8) {
        uint4 pk;
        pk.x = (unsigned)f2b(a0) | ((unsigned)f2b(a1) << 16);
        pk.y = (unsigned)f2b(a2) | ((unsigned)f2b(a3) << 16);
        pk.z = (unsigned)f2b(a4) | ((unsigned)f2b(a5) << 16);
        pk.w = (unsigned)f2b(a6) | ((unsigned)f2b(a7) << 16);
        *(uint4*)((unsigned short*)aggr + (size_t)node * 64 + fo) = pk;
    }
}

// one 64-node conv tile (verbatim R8 conv64 body): 8 waves, lane = node,
// wave jw computes j in [8jw, 8jw+8) with wave-uniform scalar W operands.
__device__ __forceinline__ void conv_tile(
    const bf16* __restrict__ h, const bf16* __restrict__ aggr,
    const float* __restrict__ he, const float* __restrict__ Wl,
    const float* __restrict__ bias, bf16* __restrict__ outp, int n_nodes,
    int act, int base, int lane, int jw) {
    const int j0 = jw * JPW;
    int node = base + lane;
    bool ok = node < n_nodes;
    int nc = ok ? node : (n_nodes - 1);

    const bf16* hrow = h + (size_t)nc * 64;
    const bf16* arow = aggr + (size_t)nc * 64;

    float acc[JPW];
#pragma unroll
    for (int jj = 0; jj < JPW; ++jj) acc[jj] = bias[j0 + jj];
    {
        float hev = he[nc];
        const float* wrow = Wl + 128 * 64 + j0;
#pragma unroll
        for (int jj = 0; jj < JPW; ++jj) acc[jj] += hev * wrow[jj];
    }
#pragma unroll 4
    for (int kc = 0; kc < 16; ++kc) {
        float4 xv = ld4(hrow, kc);
        const float* wrow = Wl + (kc * 4) * 64 + j0;
#pragma unroll
        for (int jj = 0; jj < JPW; ++jj) acc[jj] += xv.x * wrow[jj];
#pragma unroll
        for (int jj = 0; jj < JPW; ++jj) acc[jj] += xv.y * wrow[64 + jj];
#pragma unroll
        for (int jj = 0; jj < JPW; ++jj) acc[jj] += xv.z * wrow[128 + jj];
#pragma unroll
        for (int jj = 0; jj < JPW; ++jj) acc[jj] += xv.w * wrow[192 + jj];
    }
#pragma unroll 4
    for (int kc = 0; kc < 16; ++kc) {
        float4 xv = ld4(arow, kc);
        const float* wrow = Wl + (64 + kc * 4) * 64 + j0;
#pragma unroll
        for (int jj = 0; jj < JPW; ++jj) acc[jj] += xv.x * wrow[jj];
#pragma unroll
        for (int jj = 0; jj < JPW; ++jj) acc[jj] += xv.y * wrow[64 + jj];
#pragma unroll
        for (int jj = 0; jj < JPW; ++jj) acc[jj] += xv.z * wrow[128 + jj];
#pragma unroll
        for (int jj = 0; jj < JPW; ++jj) acc[jj] += xv.w * wrow[192 + jj];
    }
    if (ok) {
        unsigned short us[JPW];
#pragma unroll
        for (int jj = 0; jj < JPW; ++jj) {
            float v = acc[jj];
            if (act == 1) v = fmaxf(v, 0.f);
            else v = 1.f / (1.f + expf(-v));
            us[jj] = f2b(v);
        }
        uint4 pk;
        pk.x = (unsigned)us[0] | ((unsigned)us[1] << 16);
        pk.y = (unsigned)us[2] | ((unsigned)us[3] << 16);
        pk.z = (unsigned)us[4] | ((unsigned)us[5] << 16);
        pk.w = (unsigned)us[6] | ((unsigned)us[7] << 16);
        *(uint4*)((unsigned short*)outp + (size_t)node * 64 + j0) = pk;
    }
}

// ---------------- the whole model in one cooperative kernel ----------------
extern "C" __global__ void __launch_bounds__(512) fused_all(
    const float* __restrict__ node_feat, const float* __restrict__ edge_feat,
    const int* __restrict__ src, const int* __restrict__ dst,
    const float* __restrict__ W1, const float* __restrict__ b1,
    const float* __restrict__ Wmid, const float* __restrict__ bmid,
    const float* __restrict__ W2, const float* __restrict__ b2,
    float* __restrict__ out, float* __restrict__ he, float* __restrict__ Wt,
    bf16* __restrict__ aggr, bf16* __restrict__ hA, bf16* __restrict__ hB,
    bf16* __restrict__ nfb, unsigned* __restrict__ slots,
    int* __restrict__ deg, int N, int E) {
    cg::grid_group grid = cg::this_grid();
    const int tid = blockIdx.x * blockDim.x + threadIdx.x;
    const int T = gridDim.x * blockDim.x;
    const int lane = threadIdx.x & 63;
    const int wv = __builtin_amdgcn_readfirstlane(threadIdx.x >> 6);  // 0..7
    const int wid = blockIdx.x * 8 + wv;
    const int NW = gridDim.x * 8;

    // P1: slot fill + W transpose + node_feat -> bf16 (deg zeroed by memset)
    for (int e = tid; e < E; e += T) {
        int d = dst[e];
        int p = atomicAdd(&deg[d], 1);
        if (p < SLOTW) {
            slots[(size_t)d * SLOTW + p] =
                (unsigned)(src[e] & 0xffff) | ((unsigned)f2b(edge_feat[e]) << 16);
        }
    }
    const int per_layer = 129 * 64;
    for (int idx = tid; idx < 6 * per_layer; idx += T) {
        int l = idx / per_layer;
        int r = idx - l * per_layer;
        int k = r >> 6;
        int j = r & 63;
        const float* Wsrc = (l == 0) ? W1 : Wmid + (size_t)(l - 1) * 64 * 129;
        Wt[idx] = Wsrc[j * 129 + k];
    }
    const int n_quads = N * 16;
    for (int q = tid; q < n_quads; q += T) {
        float4 v = ((const float4*)node_feat)[q];
        ushort4 u;
        u.x = f2b(v.x); u.y = f2b(v.y); u.z = f2b(v.z); u.w = f2b(v.w);
        ((ushort4*)nfb)[q] = u;
    }
    __threadfence();
    grid.sync();

    // 6 hidden layers: gather -> sync -> conv -> sync
    const bf16* hin = nfb;
    for (int l = 0; l < 6; ++l) {
        const unsigned short* hs = (const unsigned short*)hin;
        if (l == 0) {
            for (int node = wid; node < N; node += NW)
                gather_node<true>(hs, deg, slots, aggr, he, node, lane);
        } else {
            for (int node = wid; node < N; node += NW)
                gather_node<false>(hs, deg, slots, aggr, he, node, lane);
        }
        __threadfence();
        grid.sync();

        const float* Wl = Wt + (size_t)l * 129 * 64;
        const float* bias = (l == 0) ? b1 : bmid + (size_t)(l - 1) * 64;
        int act = (l == 5) ? 2 : 1;
        bf16* hout = (l & 1) ? hB : hA;
        for (int base = blockIdx.x * 64; base < N; base += gridDim.x * 64)
            conv_tile(hin, aggr, he, Wl, bias, hout, N, act, base, lane, wv);
        __threadfence();
        grid.sync();
        hin = hout;
    }

    // final layer: gather -> sync -> 2-class conv (wave per node, R8 body)
    {
        const unsigned short* hs = (const unsigned short*)hin;
        for (int node = wid; node < N; node += NW)
            gather_node<false>(hs, deg, slots, aggr, he, node, lane);
        __threadfence();
        grid.sync();

        const unsigned short* as = (const unsigned short*)aggr;
        float w0a = W2[lane], w0b = W2[64 + lane];
        float w1a = W2[129 + lane], w1b = W2[193 + lane];
        for (int n = wid; n < N; n += NW) {
            float x0 = b2f(hs[(size_t)n * 64 + lane]);
            float x1 = b2f(as[(size_t)n * 64 + lane]);
            float s0 = w0a * x0 + w0b * x1;
            float s1 = w1a * x0 + w1b * x1;
            for (int off = 32; off; off >>= 1) {
                s0 += __shfl_down(s0, off, 64);
                s1 += __shfl_down(s1, off, 64);
            }
            if (lane == 0) {
                float hev = he[n];
                out[(size_t)n * 2] = s0 + W2[128] * hev + b2[0];
                out[(size_t)n * 2 + 1] = s1 + W2[257] * hev + b2[1];
            }
        }
    }
}

extern "C" void kernel_launch(void* const* d_in, const int* in_sizes, int n_in,
                              void* d_out, int out_size, void* d_ws,
                              size_t ws_size, hipStream_t stream) {
    const float* node_feat = (const float*)d_in[0];
    const float* edge_feat = (const float*)d_in[1];
    const int* src = (const int*)d_in[2];
    const int* dst = (const int*)d_in[3];
    const float* W1 = (const float*)d_in[4];
    const float* b1 = (const float*)d_in[5];
    const float* Wmid = (const float*)d_in[6];
    const float* bmid = (const float*)d_in[7];
    const float* W2 = (const float*)d_in[8];
    const float* b2 = (const float*)d_in[9];
    float* out = (float*)d_out;

    int N = in_sizes[0] / 64;  // 50000
    int E = in_sizes[1];       // 800000

    // workspace layout (all sections 16B-aligned)
    float* he = (float*)d_ws;                             // N f32
    float* Wt = he + N;                                   // 6*129*64 f32
    bf16* aggr = (bf16*)(Wt + 6 * 129 * 64);              // N*64 bf16
    bf16* hA = aggr + (size_t)N * 64;                     // N*64 bf16
    bf16* hB = hA + (size_t)N * 64;                       // N*64 bf16
    bf16* nfb = hB + (size_t)N * 64;                      // N*64 bf16
    unsigned* slots = (unsigned*)(nfb + (size_t)N * 64);  // N*SLOTW
    int* deg = (int*)(slots + (size_t)N * SLOTW);         // N

    hipMemsetAsync(deg, 0, (size_t)N * sizeof(int), stream);

    // grid = CUs x max co-resident blocks (cooperative requirement)
    int maxB = 0;
    hipOccupancyMaxActiveBlocksPerMultiprocessor(&maxB, (const void*)fused_all,
                                                 512, 0);
    if (maxB < 1) maxB = 1;
    if (maxB > 4) maxB = 4;
    int grid = 256 * maxB;

    void* args[] = {(void*)&node_feat, (void*)&edge_feat, (void*)&src,
                    (void*)&dst,       (void*)&W1,        (void*)&b1,
                    (void*)&Wmid,      (void*)&bmid,      (void*)&W2,
                    (void*)&b2,        (void*)&out,       (void*)&he,
                    (void*)&Wt,        (void*)&aggr,      (void*)&hA,
                    (void*)&hB,        (void*)&nfb,       (void*)&slots,
                    (void*)&deg,       (void*)&N,         (void*)&E};
    hipLaunchCooperativeKernel((const void*)fused_all, dim3(grid), dim3(512),
                               args, 0, stream);
}

// Round 13
// 416.827 us; speedup vs baseline: 5.5622x; 4.9603x over previous
//
#include <hip/hip_runtime.h>
#include <hip/hip_bf16.h>
#include <math.h>

// ---------------------------------------------------------------------------
// ModelPassMessage: 7-layer graph conv.
// R1..R6: CSR->slot-table, bf16 everywhere, LDS-free conv. 1631->419us.
// R7 FAILED: block-local gather+conv fusion (serial per-wave gather). 510us.
// R8: 4B packed slots. 413us (best).
// R9-R11 FAILED (2.1-2.3ms): cooperative whole-model fusion. grid.sync on
//     8-XCD gfx950 forces per-XCD L2 writeback/invalidate per sync -> each
//     phase re-fetches from HBM (FETCH 414-441MB) + slow cross-XCD barrier.
//     Cooperative fusion abandoned.
// R12: R8 structure + final layer fused into its gather (aggr for node n is
//     wave-local after the reduce -> no cross-block dep, no barrier): one
//     fewer dispatch, no final aggr round-trip.
// ---------------------------------------------------------------------------

typedef __hip_bfloat16 bf16;

#define SLOTW 64  // max degree supported; Poisson(16) max over 50k nodes ~45

__device__ inline float b2f(unsigned u) {
    return __uint_as_float(u << 16);
}
__device__ inline unsigned short f2b(float f) {
    union { float f; unsigned u; } v;
    v.f = f;
    unsigned r = v.u + 0x7FFF + ((v.u >> 16) & 1);  // RNE
    return (unsigned short)(r >> 16);
}

// load 4 consecutive features (chunk kc) from a 64-wide bf16 row
__device__ inline float4 ld4(const bf16* row, int kc) {
    ushort4 u = ((const ushort4*)row)[kc];
    float4 r;
    r.x = b2f(u.x); r.y = b2f(u.y); r.z = b2f(u.z); r.w = b2f(u.w);
    return r;
}

// ---------------- prep: slot-fill + W transpose + node_feat->bf16 ----------
// Grid sections: [0,HB) slot fill; [HB,HB+TB) W transpose; [HB+TB,..)
// node_feat convert. Wt[l][k][j] = W_l[j][k], 129x64 per layer.
// Slot pack: low 16 = src (N < 65536), high 16 = ef as bf16.
#define TB ((6 * 129 * 64 + 255) / 256)
__global__ void prep_kernel(const float* __restrict__ W1,
                            const float* __restrict__ Wmid,
                            float* __restrict__ Wt,
                            const float* __restrict__ node_feat,
                            bf16* __restrict__ nfb,
                            const int* __restrict__ src,
                            const int* __restrict__ dst,
                            const float* __restrict__ ef,
                            int* __restrict__ deg, unsigned* __restrict__ slots,
                            int n_edges, int n_quads /* N*64/4 */) {
    const int HB = (n_edges + 255) / 256;
    if (blockIdx.x < HB) {
        int e = blockIdx.x * 256 + threadIdx.x;
        if (e >= n_edges) return;
        int d = dst[e];
        int p = atomicAdd(&deg[d], 1);
        if (p < SLOTW) {
            unsigned pk = (unsigned)(src[e] & 0xffff) |
                          ((unsigned)f2b(ef[e]) << 16);
            slots[(size_t)d * SLOTW + p] = pk;
        }
    } else if (blockIdx.x < HB + TB) {
        int idx = (blockIdx.x - HB) * 256 + threadIdx.x;
        const int per_layer = 129 * 64;
        if (idx >= 6 * per_layer) return;
        int l = idx / per_layer;
        int r = idx - l * per_layer;
        int k = r >> 6;
        int j = r & 63;
        const float* Wsrc = (l == 0) ? W1 : Wmid + (size_t)(l - 1) * 64 * 129;
        Wt[idx] = Wsrc[j * 129 + k];
    } else {
        int q = (blockIdx.x - HB - TB) * 256 + threadIdx.x;
        if (q >= n_quads) return;
        float4 v = ((const float4*)node_feat)[q];
        ushort4 u;
        u.x = f2b(v.x); u.y = f2b(v.y); u.z = f2b(v.z); u.w = f2b(v.w);
        ((ushort4*)nfb)[q] = u;
    }
}

// ---------------- per-layer kernels ---------------------------------------

// bf16 gather: one wave per node; 8 edge-groups x 8 lanes x ushort8(16B).
// Up to 16 neighbor rows in flight per wave (unroll 2).
// HE: also reduce the bucket's edge-feature sum -> he[node] (layer 0 only).
template <bool HE>
__global__ __launch_bounds__(256) void gather_aggr_kernel(
    const bf16* __restrict__ h, const int* __restrict__ deg,
    const unsigned* __restrict__ slots, bf16* __restrict__ aggr,
    float* __restrict__ he, int n_nodes) {
    int wave = threadIdx.x >> 6;
    int lane = threadIdx.x & 63;
    int node = blockIdx.x * 4 + wave;
    if (node >= n_nodes) return;
    int e = deg[node];
    e = e < SLOTW ? e : SLOTW;
    const unsigned* row = slots + (size_t)node * SLOTW;
    const int eg = lane >> 3;       // 0..7
    const int fo = (lane & 7) * 8;  // feature offset, 8 bf16 = 16B

    float a0 = 0.f, a1 = 0.f, a2 = 0.f, a3 = 0.f;
    float a4 = 0.f, a5 = 0.f, a6 = 0.f, a7 = 0.f, efacc = 0.f;
    const unsigned short* hs = (const unsigned short*)h;
    int i = eg;
    for (; i + 8 < e; i += 16) {
        unsigned p0 = row[i];
        unsigned p1 = row[i + 8];
        uint4 u0 = *(const uint4*)(hs + (size_t)(p0 & 0xffff) * 64 + fo);
        uint4 u1 = *(const uint4*)(hs + (size_t)(p1 & 0xffff) * 64 + fo);
        if (HE) efacc += b2f(p0 >> 16) + b2f(p1 >> 16);
        a0 += b2f(u0.x & 0xffff) + b2f(u1.x & 0xffff);
        a1 += b2f(u0.x >> 16) + b2f(u1.x >> 16);
        a2 += b2f(u0.y & 0xffff) + b2f(u1.y & 0xffff);
        a3 += b2f(u0.y >> 16) + b2f(u1.y >> 16);
        a4 += b2f(u0.z & 0xffff) + b2f(u1.z & 0xffff);
        a5 += b2f(u0.z >> 16) + b2f(u1.z >> 16);
        a6 += b2f(u0.w & 0xffff) + b2f(u1.w & 0xffff);
        a7 += b2f(u0.w >> 16) + b2f(u1.w >> 16);
    }
    if (i < e) {
        unsigned p0 = row[i];
        uint4 u0 = *(const uint4*)(hs + (size_t)(p0 & 0xffff) * 64 + fo);
        if (HE) efacc += b2f(p0 >> 16);
        a0 += b2f(u0.x & 0xffff);
        a1 += b2f(u0.x >> 16);
        a2 += b2f(u0.y & 0xffff);
        a3 += b2f(u0.y >> 16);
        a4 += b2f(u0.z & 0xffff);
        a5 += b2f(u0.z >> 16);
        a6 += b2f(u0.w & 0xffff);
        a7 += b2f(u0.w >> 16);
    }
#pragma unroll
    for (int off = 32; off >= 8; off >>= 1) {
        a0 += __shfl_down(a0, off, 64);
        a1 += __shfl_down(a1, off, 64);
        a2 += __shfl_down(a2, off, 64);
        a3 += __shfl_down(a3, off, 64);
        a4 += __shfl_down(a4, off, 64);
        a5 += __shfl_down(a5, off, 64);
        a6 += __shfl_down(a6, off, 64);
        a7 += __shfl_down(a7, off, 64);
        if (HE) efacc += __shfl_down(efacc, off, 64);
    }
    if (HE && lane == 0) he[node] = efacc;
    if (lane < 8) {
        uint4 pk;
        pk.x = (unsigned)f2b(a0) | ((unsigned)f2b(a1) << 16);
        pk.y = (unsigned)f2b(a2) | ((unsigned)f2b(a3) << 16);
        pk.z = (unsigned)f2b(a4) | ((unsigned)f2b(a5) << 16);
        pk.w = (unsigned)f2b(a6) | ((unsigned)f2b(a7) << 16);
        *(uint4*)((unsigned short*)aggr + (size_t)node * 64 + fo) = pk;
    }
}

// 64-output conv layer, LDS-free. Block = 512 threads = 8 waves; lane = node,
// wave w computes output features [8w, 8w+8) with wave-uniform scalar W.
#define JPW 8
__global__ __launch_bounds__(512) void conv64_kernel(
    const bf16* __restrict__ h, const bf16* __restrict__ aggr,
    const float* __restrict__ he, const float* __restrict__ Wt,
    const float* __restrict__ b, bf16* __restrict__ out, int n_nodes,
    int act /*1 relu, 2 sigmoid*/) {
    const int lane = threadIdx.x & 63;
    const int jw = __builtin_amdgcn_readfirstlane(threadIdx.x >> 6);  // 0..7
    const int j0 = jw * JPW;

    int node = blockIdx.x * 64 + lane;
    bool ok = node < n_nodes;
    int nc = ok ? node : (n_nodes - 1);

    const bf16* hrow = h + (size_t)nc * 64;
    const bf16* arow = aggr + (size_t)nc * 64;

    float acc[JPW];
#pragma unroll
    for (int jj = 0; jj < JPW; ++jj) acc[jj] = b[j0 + jj];

    {
        float hev = he[nc];
        const float* wrow = Wt + 128 * 64 + j0;
#pragma unroll
        for (int jj = 0; jj < JPW; ++jj) acc[jj] += hev * wrow[jj];
    }

#pragma unroll 4
    for (int kc = 0; kc < 16; ++kc) {
        float4 xv = ld4(hrow, kc);
        const float* wrow = Wt + (kc * 4) * 64 + j0;
#pragma unroll
        for (int jj = 0; jj < JPW; ++jj) acc[jj] += xv.x * wrow[jj];
#pragma unroll
        for (int jj = 0; jj < JPW; ++jj) acc[jj] += xv.y * wrow[64 + jj];
#pragma unroll
        for (int jj = 0; jj < JPW; ++jj) acc[jj] += xv.z * wrow[128 + jj];
#pragma unroll
        for (int jj = 0; jj < JPW; ++jj) acc[jj] += xv.w * wrow[192 + jj];
    }
#pragma unroll 4
    for (int kc = 0; kc < 16; ++kc) {
        float4 xv = ld4(arow, kc);
        const float* wrow = Wt + (64 + kc * 4) * 64 + j0;
#pragma unroll
        for (int jj = 0; jj < JPW; ++jj) acc[jj] += xv.x * wrow[jj];
#pragma unroll
        for (int jj = 0; jj < JPW; ++jj) acc[jj] += xv.y * wrow[64 + jj];
#pragma unroll
        for (int jj = 0; jj < JPW; ++jj) acc[jj] += xv.z * wrow[128 + jj];
#pragma unroll
        for (int jj = 0; jj < JPW; ++jj) acc[jj] += xv.w * wrow[192 + jj];
    }

    if (ok) {
        unsigned short us[JPW];
#pragma unroll
        for (int jj = 0; jj < JPW; ++jj) {
            float v = acc[jj];
            if (act == 1) v = fmaxf(v, 0.f);
            else v = 1.f / (1.f + expf(-v));  // act == 2
            us[jj] = f2b(v);
        }
        uint4 pk;
        pk.x = (unsigned)us[0] | ((unsigned)us[1] << 16);
        pk.y = (unsigned)us[2] | ((unsigned)us[3] << 16);
        pk.z = (unsigned)us[4] | ((unsigned)us[5] << 16);
        pk.w = (unsigned)us[6] | ((unsigned)us[7] << 16);
        *(uint4*)((unsigned short*)out + (size_t)node * 64 + j0) = pk;
    }
}

// ---------------- fused final: gather + 2-class conv, one wave per node ----
// After the gather reduce, lanes 0..7 hold aggr features [8p,8p+8) in
// registers; the 2-class dot is computed in place. No aggr store, no second
// kernel, no barrier (dependency is wave-local).
__global__ __launch_bounds__(256) void final_fused_kernel(
    const bf16* __restrict__ h, const int* __restrict__ deg,
    const unsigned* __restrict__ slots, const float* __restrict__ he,
    const float* __restrict__ W2, const float* __restrict__ b2,
    float* __restrict__ out, int n_nodes) {
    int wave = threadIdx.x >> 6;
    int lane = threadIdx.x & 63;
    int node = blockIdx.x * 4 + wave;
    if (node >= n_nodes) return;
    int e = deg[node];
    e = e < SLOTW ? e : SLOTW;
    const unsigned* row = slots + (size_t)node * SLOTW;
    const int eg = lane >> 3;
    const int fo = (lane & 7) * 8;

    float a0 = 0.f, a1 = 0.f, a2 = 0.f, a3 = 0.f;
    float a4 = 0.f, a5 = 0.f, a6 = 0.f, a7 = 0.f;
    const unsigned short* hs = (const unsigned short*)h;
    int i = eg;
    for (; i + 8 < e; i += 16) {
        unsigned p0 = row[i];
        unsigned p1 = row[i + 8];
        uint4 u0 = *(const uint4*)(hs + (size_t)(p0 & 0xffff) * 64 + fo);
        uint4 u1 = *(const uint4*)(hs + (size_t)(p1 & 0xffff) * 64 + fo);
        a0 += b2f(u0.x & 0xffff) + b2f(u1.x & 0xffff);
        a1 += b2f(u0.x >> 16) + b2f(u1.x >> 16);
        a2 += b2f(u0.y & 0xffff) + b2f(u1.y & 0xffff);
        a3 += b2f(u0.y >> 16) + b2f(u1.y >> 16);
        a4 += b2f(u0.z & 0xffff) + b2f(u1.z & 0xffff);
        a5 += b2f(u0.z >> 16) + b2f(u1.z >> 16);
        a6 += b2f(u0.w & 0xffff) + b2f(u1.w & 0xffff);
        a7 += b2f(u0.w >> 16) + b2f(u1.w >> 16);
    }
    if (i < e) {
        unsigned p0 = row[i];
        uint4 u0 = *(const uint4*)(hs + (size_t)(p0 & 0xffff) * 64 + fo);
        a0 += b2f(u0.x & 0xffff);
        a1 += b2f(u0.x >> 16);
        a2 += b2f(u0.y & 0xffff);
        a3 += b2f(u0.y >> 16);
        a4 += b2f(u0.z & 0xffff);
        a5 += b2f(u0.z >> 16);
        a6 += b2f(u0.w & 0xffff);
        a7 += b2f(u0.w >> 16);
    }
#pragma unroll
    for (int off = 32; off >= 8; off >>= 1) {
        a0 += __shfl_down(a0, off, 64);
        a1 += __shfl_down(a1, off, 64);
        a2 += __shfl_down(a2, off, 64);
        a3 += __shfl_down(a3, off, 64);
        a4 += __shfl_down(a4, off, 64);
        a5 += __shfl_down(a5, off, 64);
        a6 += __shfl_down(a6, off, 64);
        a7 += __shfl_down(a7, off, 64);
    }
    // lanes 0..7 now hold the final aggr features [8p, 8p+8)
    const int p = lane & 7;
    float ar[8] = {a0, a1, a2, a3, a4, a5, a6, a7};
    // h features [8p, 8p+8) for this node
    uint4 hu = *(const uint4*)(hs + (size_t)node * 64 + 8 * p);
    float x0[8];
    x0[0] = b2f(hu.x & 0xffff); x0[1] = b2f(hu.x >> 16);
    x0[2] = b2f(hu.y & 0xffff); x0[3] = b2f(hu.y >> 16);
    x0[4] = b2f(hu.z & 0xffff); x0[5] = b2f(hu.z >> 16);
    x0[6] = b2f(hu.w & 0xffff); x0[7] = b2f(hu.w >> 16);
    float s0 = 0.f, s1 = 0.f;
#pragma unroll
    for (int q = 0; q < 8; ++q) {
        s0 += W2[8 * p + q] * x0[q] + W2[64 + 8 * p + q] * ar[q];
        s1 += W2[129 + 8 * p + q] * x0[q] + W2[193 + 8 * p + q] * ar[q];
    }
    if (lane >= 8) { s0 = 0.f; s1 = 0.f; }
#pragma unroll
    for (int off = 4; off; off >>= 1) {
        s0 += __shfl_down(s0, off, 64);
        s1 += __shfl_down(s1, off, 64);
    }
    if (lane == 0) {
        float hev = he[node];
        out[(size_t)node * 2] = s0 + W2[128] * hev + b2[0];
        out[(size_t)node * 2 + 1] = s1 + W2[257] * hev + b2[1];
    }
}

extern "C" void kernel_launch(void* const* d_in, const int* in_sizes, int n_in,
                              void* d_out, int out_size, void* d_ws,
                              size_t ws_size, hipStream_t stream) {
    const float* node_feat = (const float*)d_in[0];
    const float* edge_feat = (const float*)d_in[1];
    const int* src = (const int*)d_in[2];
    const int* dst = (const int*)d_in[3];
    const float* W1 = (const float*)d_in[4];
    const float* b1 = (const float*)d_in[5];
    const float* Wmid = (const float*)d_in[6];
    const float* bmid = (const float*)d_in[7];
    const float* W2 = (const float*)d_in[8];
    const float* b2 = (const float*)d_in[9];
    float* out = (float*)d_out;

    const int N = in_sizes[0] / 64;  // 50000
    const int E = in_sizes[1];       // 800000

    // workspace layout (all sections 16B-aligned)
    float* he = (float*)d_ws;                          // N f32
    float* Wt = he + N;                                // 6*129*64 f32
    bf16* aggr = (bf16*)(Wt + 6 * 129 * 64);           // N*64 bf16
    bf16* hA = aggr + (size_t)N * 64;                  // N*64 bf16
    bf16* hB = hA + (size_t)N * 64;                    // N*64 bf16
    bf16* nfb = hB + (size_t)N * 64;                   // N*64 bf16
    unsigned* slots = (unsigned*)(nfb + (size_t)N * 64);  // N*SLOTW (12.8 MB)
    int* deg = (int*)(slots + (size_t)N * SLOTW);      // N

    // --- prep: zero deg, then slot-fill + W transpose + nf->bf16 ---
    hipMemsetAsync(deg, 0, (size_t)N * sizeof(int), stream);
    const int HB = (E + 255) / 256;
    const int n_quads = N * 16;
    const int CB = (n_quads + 255) / 256;
    prep_kernel<<<HB + TB + CB, 256, 0, stream>>>(W1, Wmid, Wt, node_feat, nfb,
                                                  src, dst, edge_feat, deg,
                                                  slots, E, n_quads);

    // --- 7 layers ---
    const int conv_blocks = (N + 63) / 64;
    const int gather_blocks = (N + 3) / 4;

    // layer 0 (bf16 node features; computes he on the fly)
    gather_aggr_kernel<true><<<gather_blocks, 256, 0, stream>>>(
        nfb, deg, slots, aggr, he, N);
    conv64_kernel<<<conv_blocks, 512, 0, stream>>>(nfb, aggr, he, Wt, b1, hA,
                                                   N, 1);

    // layers 1..5
    bf16* bufs[2] = {hA, hB};
    const bf16* hin = hA;
    for (int l = 1; l < 6; ++l) {
        gather_aggr_kernel<false><<<gather_blocks, 256, 0, stream>>>(
            hin, deg, slots, aggr, he, N);
        int act = (l - 1) < 4 ? 1 : 2;  // mid layers 0..3 relu, 4 sigmoid
        bf16* hout = bufs[l & 1];
        conv64_kernel<<<conv_blocks, 512, 0, stream>>>(
            hin, aggr, he, Wt + (size_t)l * 129 * 64,
            bmid + (size_t)(l - 1) * 64, hout, N, act);
        hin = hout;
    }

    // fused final layer (gather + 2-class conv in one kernel)
    final_fused_kernel<<<gather_blocks, 256, 0, stream>>>(hin, deg, slots, he,
                                                          W2, b2, out, N);
}